// Round 9
// baseline (289.700 us; speedup 1.0000x reference)
//
#include <hip/hip_runtime.h>
#include <hip/hip_bf16.h>
#include <stdint.h>

#define E_IN_N   1048576
#define E_OUT_N  131072
#define KTAPS    9
#define CIN      64
#define COUT     64
#define NCELL    (E_OUT_N*KTAPS)   /* 1179648 */
#define NB_SCAN  1152              /* NCELL/1024 */
#define TILE_E   32
#define NKSTEP   18                /* 576/32 */
#define CHUNK    16

typedef __attribute__((ext_vector_type(8))) short bf16x8;
typedef __attribute__((ext_vector_type(4))) float f32x4;

__device__ __forceinline__ ushort f32_bf16(float x){
  union{float f; uint32_t u;} v; v.f=x;
  uint32_t r = v.u + 0x7FFFu + ((v.u>>16)&1u);
  return (ushort)(r>>16);
}

// fused: zero counts (blocks 0..1151) + W pre-permute (1152..1295)
__global__ void prep_k(int* __restrict__ counts, const float* __restrict__ wk,
                       ushort* __restrict__ wb){
  int b=blockIdx.x, t=threadIdx.x;
  if(b<1152){
    ((int4*)counts)[b*256+t]=int4{0,0,0,0};
  }else{
    int slot=(b-1152)*256+t;                 // 36864 total
    int j=slot&7; int t2=slot>>3; int lane=t2&63; int t3=t2>>6;
    int ks=t3%NKSTEP; int nt=t3/NKSTEP;
    int r=ks*32+((lane>>4)*8)+j; int col=nt*16+(lane&15);
    wb[slot]=f32_bf16(wk[r*COUT+col]);
  }
}

// histogram + per-event rank; cellrank = cell<<11 | rank  (cell<2^21, rank<2048)
__global__ void hist_k(const int* __restrict__ seg, const int* __restrict__ succ,
                       int* __restrict__ counts, uint32_t* __restrict__ cellrank){
  int i = blockIdx.x*256 + threadIdx.x;
  uint32_t cell = (uint32_t)(seg[i]*KTAPS + succ[i]);
  uint32_t rank = (uint32_t)atomicAdd(&counts[cell],1);
  cellrank[i] = (cell<<11) | rank;
}

__global__ void blocksum_k(const int* __restrict__ counts, int* __restrict__ bsum){
  __shared__ int sm[256];
  int b=blockIdx.x, t=threadIdx.x;
  const int4 c4 = *(const int4*)(counts + b*1024 + t*4);
  int s=c4.x+c4.y+c4.z+c4.w;
  sm[t]=s; __syncthreads();
  for(int d=128; d>0; d>>=1){ if(t<d) sm[t]+=sm[t+d]; __syncthreads(); }
  if(t==0) bsum[b]=sm[0];
}

// fused: block prefix over bsum + intra-block scan of counts -> offsets
__global__ void offsets_k(const int* __restrict__ counts, const int* __restrict__ bsum,
                          int* __restrict__ offsets){
  __shared__ int sm[256];
  int b=blockIdx.x, t=threadIdx.x;
  int s=0;
  for(int j=t; j<NB_SCAN; j+=256) if(j<b) s+=bsum[j];
  sm[t]=s; __syncthreads();
  for(int d=128; d>0; d>>=1){ if(t<d) sm[t]+=sm[t+d]; __syncthreads(); }
  int base0=sm[0]; __syncthreads();
  int base=b*1024+t*4;
  const int4 c4=*(const int4*)(counts+base);
  int s2=c4.x+c4.y+c4.z+c4.w;
  sm[t]=s2; __syncthreads();
  for(int d=1; d<256; d<<=1){ int x=(t>=d)?sm[t-d]:0; __syncthreads(); sm[t]+=x; __syncthreads(); }
  int e0v=base0 + ((t==0)?0:sm[t-1]);
  int4 o; o.x=e0v; o.y=e0v+c4.x; o.z=o.y+c4.y; o.w=o.z+c4.z;
  *(int4*)(offsets+base)=o;
  if(b==NB_SCAN-1 && t==255) offsets[NCELL]=o.w+c4.w;
}

// Stream features (coalesced f32 read), write bf16 rows to SORTED positions
// (random 128 B writes: fire-and-forget), fused payload write {rel<<20, dt}.
// 8 rows per 256-thread block; 32 lanes/row, 2 channels/lane.
__global__ void scatterF_k(const float* __restrict__ features, const float* __restrict__ dtv,
                           const uint32_t* __restrict__ cellrank, const int* __restrict__ offsets,
                           uint32_t* __restrict__ sortedF, int2* __restrict__ sorted2){
  const int r = blockIdx.x*8 + (threadIdx.x>>5);   // event/row index
  const int l = threadIdx.x&31;                    // channels 2l, 2l+1
  uint32_t cr = cellrank[r];
  uint32_t cell = cr>>11, rank = cr&2047u;
  int pos = offsets[cell] + (int)rank;
  float2 f2 = *(const float2*)(features + ((size_t)r<<6) + 2*l);
  uint32_t packed = ((uint32_t)f32_bf16(f2.y)<<16) | (uint32_t)f32_bf16(f2.x);
  sortedF[((size_t)pos<<5) + l] = packed;          // 128 B contiguous per row
  if(l==0){
    uint32_t x=cell>>5;
    uint32_t q=__umulhi(x,477218592u);             // /9 (exact for x<2^27)
    uint32_t rel=cell - q*288u;                    // cell % 288 (block-local)
    sorted2[pos]=int2{(int)(rel<<20), __float_as_int(dtv[r])};
  }
}

__global__ __launch_bounds__(512,4) void compute_k(
    const float* __restrict__ decay, const float* __restrict__ bias,
    const int* __restrict__ offsets, const int2* __restrict__ sorted2,
    const ushort* __restrict__ sortedF, const ushort* __restrict__ wb,
    float* __restrict__ out)
{
  __shared__ ushort agg[TILE_E*584];   // 576 + 8 pad per row
  const int tid=threadIdx.x, wv=tid>>6, lane=tid&63;
  const int e0=blockIdx.x*TILE_E;
  const int cb0=e0*KTAPS;

  for(int i=tid;i<TILE_E*584/2;i+=512) ((uint32_t*)agg)[i]=0u;
  float x=decay[lane];
  float rate=fmaxf(x,0.f)+log1pf(__expf(-fabsf(x)));   // softplus
  __syncthreads();

  // ---- aggregation: wave owns 36 contiguous cells; ALL reads sequential ----
  {
    const int c0=cb0+wv*36;
    int jv=0; if(lane<2) jv=offsets[c0+lane*36];
    int cb = __builtin_amdgcn_readfirstlane(__shfl(jv,0));
    const int jE = __builtin_amdgcn_readfirstlane(__shfl(jv,1));

    int prevRel=-1;
    float num=0.f, den=1.f;

    while(cb<jE){
      int qx[CHUNK]; float qd[CHUNK];
      #pragma unroll
      for(int e=0;e<CHUNK;e++){            // uniform base -> scalar loads
        int2 t=sorted2[cb+e];
        qx[e]=t.x; qd[e]=__int_as_float(t.y);
      }
      ushort us[CHUNK];
      #pragma unroll
      for(int e=0;e<CHUNK;e++)             // sequential 128 B rows, 16 in flight
        us[e]=sortedF[((size_t)(cb+e)<<6) + lane];
      #pragma unroll
      for(int e=0;e<CHUNK;e++){
        const int ok = (cb+e) < jE;        // scalar
        int rel = (int)(((uint32_t)qx[e])>>20);
        rel = ok ? rel : prevRel;          // pad: repeat last cell (harmless rewrite)
        float w = __expf(-qd[e]*rate);
        w = ok ? w : 0.f;                  // select AFTER exp: kills inf/NaN from pad garbage
        float f = __uint_as_float(((uint32_t)us[e])<<16);
        const float same = (rel==prevRel) ? 1.f : 0.f;
        num = num*same + w*f;
        den = den*same + w;
        const int le=(rel*7282)>>16, kk=rel-le*9;
        agg[le*584 + kk*64 + lane] = f32_bf16(num*__builtin_amdgcn_rcpf(den));
        prevRel = rel;
      }
      cb += CHUNK;
    }
  }
  __syncthreads();

  // ---- GEMM: wave tile = 16 rows (mt) x 16 cols (nt), K=576 ----
  const int mt=wv>>2, nt=wv&3;
  const int arow=mt*16+(lane&15);
  const int koff=(lane>>4)*8;
  const ushort* wbp = wb + ((size_t)(nt*NKSTEP)*64 + (size_t)lane)*8;
  f32x4 acc={0.f,0.f,0.f,0.f};
  #pragma unroll
  for(int ks=0;ks<NKSTEP;ks++){
    bf16x8 a=*(const bf16x8*)&agg[arow*584+ks*32+koff];
    bf16x8 bfr=*(const bf16x8*)(wbp + (size_t)ks*512);
    acc=__builtin_amdgcn_mfma_f32_16x16x32_bf16(a,bfr,acc,0,0,0);
  }
  const int orow=e0+mt*16+((lane>>4)*4);
  const int ocol=nt*16+(lane&15);
  const float bv=bias[ocol];
  #pragma unroll
  for(int r=0;r<4;r++) out[(size_t)(orow+r)*COUT+ocol]=acc[r]+bv;
}

extern "C" void kernel_launch(void* const* d_in, const int* in_sizes, int n_in,
                              void* d_out, int out_size, void* d_ws, size_t ws_size,
                              hipStream_t stream){
  const float* features=(const float*)d_in[0];
  const float* dtv=(const float*)d_in[1];
  const float* decay=(const float*)d_in[3];
  const float* wk=(const float*)d_in[4];
  const float* bias=(const float*)d_in[5];
  const int* succ=(const int*)d_in[6];
  const int* seg=(const int*)d_in[7];

  char* ws=(char*)d_ws;
  size_t o=0;
  int* counts=(int*)(ws+o);      o+=(size_t)NCELL*4;
  int* offsets=(int*)(ws+o);     o+=(size_t)(NCELL+4)*4;
  int* bsum=(int*)(ws+o);        o+=(size_t)NB_SCAN*4;
  uint32_t* cellrank=(uint32_t*)(ws+o); o+=(size_t)E_IN_N*4;
  int2* sorted2=(int2*)(ws+o);   o+=(size_t)(E_IN_N+CHUNK)*8;       // slack for padded reads
  uint32_t* sortedF=(uint32_t*)(ws+o); o+=(size_t)(E_IN_N+CHUNK)*128; // bf16 rows, 128 B each
  ushort* wb=(ushort*)(ws+o);    o+=(size_t)36864*2;
  float* out=(float*)d_out;

  hipLaunchKernelGGL(prep_k, dim3(1296),dim3(256),0,stream, counts,wk,wb);
  hipLaunchKernelGGL(hist_k, dim3(E_IN_N/256),dim3(256),0,stream, seg,succ,counts,cellrank);
  hipLaunchKernelGGL(blocksum_k, dim3(NB_SCAN),dim3(256),0,stream, counts,bsum);
  hipLaunchKernelGGL(offsets_k, dim3(NB_SCAN),dim3(256),0,stream, counts,bsum,offsets);
  hipLaunchKernelGGL(scatterF_k, dim3(E_IN_N/8),dim3(256),0,stream,
                     features,dtv,cellrank,offsets,sortedF,sorted2);
  hipLaunchKernelGGL(compute_k, dim3(E_OUT_N/TILE_E),dim3(512),0,stream,
                     decay,bias,offsets,sorted2,(const ushort*)sortedF,wb,out);
}

// Round 11
// 206.316 us; speedup vs baseline: 1.4042x; 1.4042x over previous
//
#include <hip/hip_runtime.h>
#include <hip/hip_bf16.h>
#include <stdint.h>

#define E_IN_N   1048576
#define E_OUT_N  131072
#define KTAPS    9
#define CIN      64
#define COUT     64
#define NCELL    (E_OUT_N*KTAPS)   /* 1179648 */
#define NB_SCAN  1152              /* NCELL/1024 */
#define TILE_E   32
#define NKSTEP   18                /* 576/32 */
#define CHUNK    16

typedef __attribute__((ext_vector_type(8))) short bf16x8;
typedef __attribute__((ext_vector_type(4))) float f32x4;

__device__ __forceinline__ ushort f32_bf16(float x){
  union{float f; uint32_t u;} v; v.f=x;
  uint32_t r = v.u + 0x7FFFu + ((v.u>>16)&1u);
  return (ushort)(r>>16);
}

// fused: zero counts (blocks 0..1151) + W pre-permute (1152..1295)
__global__ void prep_k(int* __restrict__ counts, const float* __restrict__ wk,
                       ushort* __restrict__ wb){
  int b=blockIdx.x, t=threadIdx.x;
  if(b<1152){
    ((int4*)counts)[b*256+t]=int4{0,0,0,0};
  }else{
    int slot=(b-1152)*256+t;                 // 36864 total
    int j=slot&7; int t2=slot>>3; int lane=t2&63; int t3=t2>>6;
    int ks=t3%NKSTEP; int nt=t3/NKSTEP;
    int r=ks*32+((lane>>4)*8)+j; int col=nt*16+(lane&15);
    wb[slot]=f32_bf16(wk[r*COUT+col]);
  }
}

// histogram + rank  AND  f32->bf16 feature conversion (sequential stream).
// featB (134 MB) becomes L3-resident so compute_k's random gathers hit L3.
__global__ void histcvt_k(const int* __restrict__ seg, const int* __restrict__ succ,
                          int* __restrict__ counts, uint32_t* __restrict__ cellrank,
                          const float* __restrict__ features, uint32_t* __restrict__ featB){
  int b=blockIdx.x, t=threadIdx.x;
  int i = b*256 + t;
  uint32_t cell = (uint32_t)(seg[i]*KTAPS + succ[i]);
  uint32_t rank = (uint32_t)atomicAdd(&counts[cell],1);
  cellrank[i] = (cell<<11) | rank;
  // convert this block's 256 events' features: 8192 u32 outputs, coalesced
  const float2* src = (const float2*)(features + ((size_t)b<<14));
  uint32_t* dst = featB + ((size_t)b<<13);
  #pragma unroll
  for(int k=0;k<32;k++){
    float2 f2 = src[k*256 + t];
    dst[k*256 + t] = ((uint32_t)f32_bf16(f2.y)<<16) | (uint32_t)f32_bf16(f2.x);
  }
}

__global__ void blocksum_k(const int* __restrict__ counts, int* __restrict__ bsum){
  __shared__ int sm[256];
  int b=blockIdx.x, t=threadIdx.x;
  const int4 c4 = *(const int4*)(counts + b*1024 + t*4);
  int s=c4.x+c4.y+c4.z+c4.w;
  sm[t]=s; __syncthreads();
  for(int d=128; d>0; d>>=1){ if(t<d) sm[t]+=sm[t+d]; __syncthreads(); }
  if(t==0) bsum[b]=sm[0];
}

// fused: block prefix over bsum + intra-block scan of counts -> offsets
__global__ void offsets_k(const int* __restrict__ counts, const int* __restrict__ bsum,
                          int* __restrict__ offsets){
  __shared__ int sm[256];
  int b=blockIdx.x, t=threadIdx.x;
  int s=0;
  for(int j=t; j<NB_SCAN; j+=256) if(j<b) s+=bsum[j];
  sm[t]=s; __syncthreads();
  for(int d=128; d>0; d>>=1){ if(t<d) sm[t]+=sm[t+d]; __syncthreads(); }
  int base0=sm[0]; __syncthreads();
  int base=b*1024+t*4;
  const int4 c4=*(const int4*)(counts+base);
  int s2=c4.x+c4.y+c4.z+c4.w;
  sm[t]=s2; __syncthreads();
  for(int d=1; d<256; d<<=1){ int x=(t>=d)?sm[t-d]:0; __syncthreads(); sm[t]+=x; __syncthreads(); }
  int e0v=base0 + ((t==0)?0:sm[t-1]);
  int4 o; o.x=e0v; o.y=e0v+c4.x; o.z=o.y+c4.y; o.w=o.z+c4.z;
  *(int4*)(offsets+base)=o;
  if(b==NB_SCAN-1 && t==255) offsets[NCELL]=o.w+c4.w;
}

// place payload: pos = offsets[cell] + rank; payload = idx|(cell%288)<<20, dt
// (sorted2 footprint 8.5 MB -> random writes L3-absorbed, proven cheap)
__global__ void scatter_k(const uint32_t* __restrict__ cellrank, const float* __restrict__ dtv,
                          const int* __restrict__ offsets, int2* __restrict__ sorted2){
  int i=blockIdx.x*256+threadIdx.x;
  uint32_t cr=cellrank[i];
  uint32_t cell=cr>>11, rank=cr&2047u;
  int base=offsets[cell];
  float d=dtv[i];
  uint32_t x=cell>>5;
  uint32_t q=__umulhi(x,477218592u);          // /9  (exact for x<2^27)
  uint32_t rel=cell - q*288u;                 // cell % 288 (block-local)
  sorted2[base+(int)rank]=int2{(int)((uint32_t)i | (rel<<20)), __float_as_int(d)};
}

__global__ __launch_bounds__(512,4) void compute_k(
    const float* __restrict__ decay, const float* __restrict__ bias,
    const int* __restrict__ offsets, const int2* __restrict__ sorted2,
    const ushort* __restrict__ featB, const ushort* __restrict__ wb,
    float* __restrict__ out)
{
  __shared__ ushort agg[TILE_E*584];   // 576 + 8 pad per row
  const int tid=threadIdx.x, wv=tid>>6, lane=tid&63;
  const int e0=blockIdx.x*TILE_E;
  const int cb0=e0*KTAPS;

  for(int i=tid;i<TILE_E*584/2;i+=512) ((uint32_t*)agg)[i]=0u;
  float x=decay[lane];
  float rate=fmaxf(x,0.f)+log1pf(__expf(-fabsf(x)));   // softplus
  __syncthreads();

  // ---- aggregation: wave owns 36 contiguous cells; gathers hit L3-resident featB ----
  {
    const int c0=cb0+wv*36;
    int jv=0; if(lane<2) jv=offsets[c0+lane*36];
    int cb = __builtin_amdgcn_readfirstlane(__shfl(jv,0));
    const int jE = __builtin_amdgcn_readfirstlane(__shfl(jv,1));

    int prevRel=-1;
    float num=0.f, den=1.f;

    while(cb<jE){
      int qx[CHUNK]; float qd[CHUNK];
      #pragma unroll
      for(int e=0;e<CHUNK;e++){            // uniform base -> scalar loads
        int2 t=sorted2[cb+e];
        qx[e]=t.x; qd[e]=__int_as_float(t.y);
      }
      ushort us[CHUNK];
      #pragma unroll
      for(int e=0;e<CHUNK;e++){            // 16 independent 128 B row-gathers in flight
        int iu = qx[e] & 0xFFFFF;          // idx < 2^20 == E_IN, always in-bounds
        us[e] = featB[((size_t)iu<<6) + lane];
      }
      #pragma unroll
      for(int e=0;e<CHUNK;e++){
        const int ok = (cb+e) < jE;        // scalar
        int rel = (int)(((uint32_t)qx[e])>>20) & 511;
        rel = ok ? rel : prevRel;          // pad: repeat last cell (harmless rewrite)
        float w = __expf(-qd[e]*rate);
        w = ok ? w : 0.f;                  // select AFTER exp: kills inf/NaN from pad garbage
        float f = __uint_as_float(((uint32_t)us[e])<<16);
        const float same = (rel==prevRel) ? 1.f : 0.f;
        num = num*same + w*f;
        den = den*same + w;
        const int le=(rel*7282)>>16, kk=rel-le*9;
        agg[le*584 + kk*64 + lane] = f32_bf16(num*__builtin_amdgcn_rcpf(den));
        prevRel = rel;
      }
      cb += CHUNK;
    }
  }
  __syncthreads();

  // ---- GEMM: wave tile = 16 rows (mt) x 16 cols (nt), K=576 ----
  const int mt=wv>>2, nt=wv&3;
  const int arow=mt*16+(lane&15);
  const int koff=(lane>>4)*8;
  const ushort* wbp = wb + ((size_t)(nt*NKSTEP)*64 + (size_t)lane)*8;
  f32x4 acc={0.f,0.f,0.f,0.f};
  #pragma unroll
  for(int ks=0;ks<NKSTEP;ks++){
    bf16x8 a=*(const bf16x8*)&agg[arow*584+ks*32+koff];
    bf16x8 bfr=*(const bf16x8*)(wbp + (size_t)ks*512);
    acc=__builtin_amdgcn_mfma_f32_16x16x32_bf16(a,bfr,acc,0,0,0);
  }
  const int orow=e0+mt*16+((lane>>4)*4);
  const int ocol=nt*16+(lane&15);
  const float bv=bias[ocol];
  #pragma unroll
  for(int r=0;r<4;r++) out[(size_t)(orow+r)*COUT+ocol]=acc[r]+bv;
}

extern "C" void kernel_launch(void* const* d_in, const int* in_sizes, int n_in,
                              void* d_out, int out_size, void* d_ws, size_t ws_size,
                              hipStream_t stream){
  const float* features=(const float*)d_in[0];
  const float* dtv=(const float*)d_in[1];
  const float* decay=(const float*)d_in[3];
  const float* wk=(const float*)d_in[4];
  const float* bias=(const float*)d_in[5];
  const int* succ=(const int*)d_in[6];
  const int* seg=(const int*)d_in[7];

  char* ws=(char*)d_ws;
  size_t o=0;
  int* counts=(int*)(ws+o);      o+=(size_t)NCELL*4;
  int* offsets=(int*)(ws+o);     o+=(size_t)(NCELL+4)*4;
  int* bsum=(int*)(ws+o);        o+=(size_t)NB_SCAN*4;
  uint32_t* cellrank=(uint32_t*)(ws+o); o+=(size_t)E_IN_N*4;
  int2* sorted2=(int2*)(ws+o);   o+=(size_t)(E_IN_N+CHUNK)*8;        // slack for padded reads
  uint32_t* featB=(uint32_t*)(ws+o); o+=(size_t)E_IN_N*128 + 4096;   // bf16 rows, 128 B each
  ushort* wb=(ushort*)(ws+o);    o+=(size_t)36864*2;
  float* out=(float*)d_out;

  hipLaunchKernelGGL(prep_k, dim3(1296),dim3(256),0,stream, counts,wk,wb);
  hipLaunchKernelGGL(histcvt_k, dim3(E_IN_N/256),dim3(256),0,stream,
                     seg,succ,counts,cellrank,features,featB);
  hipLaunchKernelGGL(blocksum_k, dim3(NB_SCAN),dim3(256),0,stream, counts,bsum);
  hipLaunchKernelGGL(offsets_k, dim3(NB_SCAN),dim3(256),0,stream, counts,bsum,offsets);
  hipLaunchKernelGGL(scatter_k, dim3(E_IN_N/256),dim3(256),0,stream, cellrank,dtv,offsets,sorted2);
  hipLaunchKernelGGL(compute_k, dim3(E_OUT_N/TILE_E),dim3(512),0,stream,
                     decay,bias,offsets,sorted2,(const ushort*)featB,wb,out);
}

// Round 14
// 184.452 us; speedup vs baseline: 1.5706x; 1.1185x over previous
//
#include <hip/hip_runtime.h>
#include <hip/hip_bf16.h>
#include <stdint.h>

#define E_IN_N   1048576
#define E_OUT_N  131072
#define KTAPS    9
#define CIN      64
#define COUT     64
#define NCELL    (E_OUT_N*KTAPS)   /* 1179648 */
#define NB_SCAN  1152              /* NCELL/1024 */
#define TILE_E   32
#define NKSTEP   18                /* 576/32 */
#define CHUNK    16

typedef __attribute__((ext_vector_type(8))) short bf16x8;
typedef __attribute__((ext_vector_type(4))) float f32x4;

__device__ __forceinline__ ushort f32_bf16(float x){
  union{float f; uint32_t u;} v; v.f=x;
  uint32_t r = v.u + 0x7FFFu + ((v.u>>16)&1u);
  return (ushort)(r>>16);
}

// fused: zero counts (blocks 0..1151) + W pre-permute (1152..1295)
__global__ void prep_k(int* __restrict__ counts, const float* __restrict__ wk,
                       ushort* __restrict__ wb){
  int b=blockIdx.x, t=threadIdx.x;
  if(b<1152){
    ((int4*)counts)[b*256+t]=int4{0,0,0,0};
  }else{
    int slot=(b-1152)*256+t;                 // 36864 total
    int j=slot&7; int t2=slot>>3; int lane=t2&63; int t3=t2>>6;
    int ks=t3%NKSTEP; int nt=t3/NKSTEP;
    int r=ks*32+((lane>>4)*8)+j; int col=nt*16+(lane&15);
    wb[slot]=f32_bf16(wk[r*COUT+col]);
  }
}

// histogram + per-event rank; cellrank = cell<<11 | rank  (cell<2^21, rank<2048)
__global__ void hist_k(const int* __restrict__ seg, const int* __restrict__ succ,
                       int* __restrict__ counts, uint32_t* __restrict__ cellrank){
  int i = blockIdx.x*256 + threadIdx.x;
  uint32_t cell = (uint32_t)(seg[i]*KTAPS + succ[i]);
  uint32_t rank = (uint32_t)atomicAdd(&counts[cell],1);
  cellrank[i] = (cell<<11) | rank;
}

__global__ void blocksum_k(const int* __restrict__ counts, int* __restrict__ bsum){
  __shared__ int sm[256];
  int b=blockIdx.x, t=threadIdx.x;
  const int4 c4 = *(const int4*)(counts + b*1024 + t*4);
  int s=c4.x+c4.y+c4.z+c4.w;
  sm[t]=s; __syncthreads();
  for(int d=128; d>0; d>>=1){ if(t<d) sm[t]+=sm[t+d]; __syncthreads(); }
  if(t==0) bsum[b]=sm[0];
}

// fused: block prefix over bsum + intra-block scan of counts -> offsets
__global__ void offsets_k(const int* __restrict__ counts, const int* __restrict__ bsum,
                          int* __restrict__ offsets){
  __shared__ int sm[256];
  int b=blockIdx.x, t=threadIdx.x;
  int s=0;
  for(int j=t; j<NB_SCAN; j+=256) if(j<b) s+=bsum[j];
  sm[t]=s; __syncthreads();
  for(int d=128; d>0; d>>=1){ if(t<d) sm[t]+=sm[t+d]; __syncthreads(); }
  int base0=sm[0]; __syncthreads();
  int base=b*1024+t*4;
  const int4 c4=*(const int4*)(counts+base);
  int s2=c4.x+c4.y+c4.z+c4.w;
  sm[t]=s2; __syncthreads();
  for(int d=1; d<256; d<<=1){ int x=(t>=d)?sm[t-d]:0; __syncthreads(); sm[t]+=x; __syncthreads(); }
  int e0v=base0 + ((t==0)?0:sm[t-1]);
  int4 o; o.x=e0v; o.y=e0v+c4.x; o.z=o.y+c4.y; o.w=o.z+c4.z;
  *(int4*)(offsets+base)=o;
  if(b==NB_SCAN-1 && t==255) offsets[NCELL]=o.w+c4.w;
}

// place events: pos = offsets[cell] + rank (no atomics); payload = idx|(cell%288)<<20, dt
__global__ void scatter_k(const uint32_t* __restrict__ cellrank, const float* __restrict__ dtv,
                          const int* __restrict__ offsets, int2* __restrict__ sorted2){
  int i=blockIdx.x*256+threadIdx.x;
  uint32_t cr=cellrank[i];
  uint32_t cell=cr>>11, rank=cr&2047u;
  int base=offsets[cell];
  float d=dtv[i];
  uint32_t x=cell>>5;
  uint32_t q=__umulhi(x,477218592u);          // /9  (exact for x<2^27)
  uint32_t rel=cell - q*288u;                 // cell % 288 (block-local)
  sorted2[base+(int)rank]=int2{(int)((uint32_t)i | (rel<<20)), __float_as_int(d)};
}

// -------- compute_k pipeline macros (A/B named buffers, static indexing) --------
#define LOADP(QX,QD,BASE) { \
  _Pragma("unroll") \
  for(int e=0;e<CHUNK;e++){ int2 t=sorted2[(BASE)+e]; QX[e]=t.x; QD[e]=__int_as_float(t.y); } }

#define GATHER(FL,QX) { \
  _Pragma("unroll") \
  for(int e=0;e<CHUNK;e++){ int iu=QX[e]&0xFFFFF; FL[e]=features[((size_t)iu<<6)+lane]; } \
  __builtin_amdgcn_sched_barrier(0); }

#define CONSUME(FL,QX,QD,BASE) { \
  _Pragma("unroll") \
  for(int e=0;e<CHUNK;e++){ \
    const int ok=(BASE)+e<jE; \
    int rel=(int)(((uint32_t)QX[e])>>20); \
    rel = ok?rel:prevRel; \
    float w=__expf(-QD[e]*rate); \
    w = ok?w:0.f; \
    const float same=(rel==prevRel)?1.f:0.f; \
    num=num*same+w*FL[e]; \
    den=den*same+w; \
    const int le=(rel*7282)>>16, kk=rel-le*9; \
    agg[le*584+kk*64+lane]=f32_bf16(num*__builtin_amdgcn_rcpf(den)); \
    prevRel=rel; \
  } }

__global__ __launch_bounds__(512,4) void compute_k(
    const float* __restrict__ features, const float* __restrict__ decay,
    const float* __restrict__ bias, const int* __restrict__ offsets,
    const int2* __restrict__ sorted2, const ushort* __restrict__ wb,
    float* __restrict__ out)
{
  __shared__ ushort agg[TILE_E*584];   // 576 + 8 pad per row
  const int tid=threadIdx.x, wv=tid>>6, lane=tid&63;
  const int e0=blockIdx.x*TILE_E;
  const int cb0=e0*KTAPS;

  for(int i=tid;i<TILE_E*584/2;i+=512) ((uint32_t*)agg)[i]=0u;
  float x=decay[lane];
  float rate=fmaxf(x,0.f)+log1pf(__expf(-fabsf(x)));   // softplus
  __syncthreads();

  // ---- aggregation: wave owns 36 contiguous cells; depth-2 pipelined chunks ----
  {
    const int c0=cb0+wv*36;
    int jv=0; if(lane<2) jv=offsets[c0+lane*36];
    int cb = __builtin_amdgcn_readfirstlane(__shfl(jv,0));
    const int jE = __builtin_amdgcn_readfirstlane(__shfl(jv,1));

    int prevRel=-1;
    float num=0.f, den=1.f;

    if(cb<jE){
      int xA[CHUNK]; float dA[CHUNK]; float fA[CHUNK];
      int xB[CHUNK]; float dB[CHUNK]; float fB[CHUNK];
      LOADP(xA,dA,cb)
      GATHER(fA,xA)
      LOADP(xB,dB,cb+CHUNK)
      while(true){
        GATHER(fB,xB)                  // next chunk's gathers fly during consume
        CONSUME(fA,xA,dA,cb)
        cb+=CHUNK; if(cb>=jE) break;
        LOADP(xA,dA,cb+CHUNK)          // payload chunk+2 (scalar, hides under next consume)
        GATHER(fA,xA)
        CONSUME(fB,xB,dB,cb)
        cb+=CHUNK; if(cb>=jE) break;
        LOADP(xB,dB,cb+CHUNK)
      }
    }
  }
  __syncthreads();

  // ---- GEMM: wave tile = 16 rows (mt) x 16 cols (nt), K=576 ----
  const int mt=wv>>2, nt=wv&3;
  const int arow=mt*16+(lane&15);
  const int koff=(lane>>4)*8;
  const ushort* wbp = wb + ((size_t)(nt*NKSTEP)*64 + (size_t)lane)*8;
  f32x4 acc={0.f,0.f,0.f,0.f};
  #pragma unroll
  for(int ks=0;ks<NKSTEP;ks++){
    bf16x8 a=*(const bf16x8*)&agg[arow*584+ks*32+koff];
    bf16x8 bfr=*(const bf16x8*)(wbp + (size_t)ks*512);
    acc=__builtin_amdgcn_mfma_f32_16x16x32_bf16(a,bfr,acc,0,0,0);
  }
  const int orow=e0+mt*16+((lane>>4)*4);
  const int ocol=nt*16+(lane&15);
  const float bv=bias[ocol];
  #pragma unroll
  for(int r=0;r<4;r++) out[(size_t)(orow+r)*COUT+ocol]=acc[r]+bv;
}

extern "C" void kernel_launch(void* const* d_in, const int* in_sizes, int n_in,
                              void* d_out, int out_size, void* d_ws, size_t ws_size,
                              hipStream_t stream){
  const float* features=(const float*)d_in[0];
  const float* dtv=(const float*)d_in[1];
  const float* decay=(const float*)d_in[3];
  const float* wk=(const float*)d_in[4];
  const float* bias=(const float*)d_in[5];
  const int* succ=(const int*)d_in[6];
  const int* seg=(const int*)d_in[7];

  char* ws=(char*)d_ws;
  size_t o=0;
  int* counts=(int*)(ws+o);      o+=(size_t)NCELL*4;
  int* offsets=(int*)(ws+o);     o+=(size_t)(NCELL+4)*4;
  int* bsum=(int*)(ws+o);        o+=(size_t)NB_SCAN*4;
  uint32_t* cellrank=(uint32_t*)(ws+o); o+=(size_t)E_IN_N*4;
  int2* sorted2=(int2*)(ws+o);   o+=(size_t)(E_IN_N+64)*8;   // slack for 2-chunk look-ahead
  ushort* wb=(ushort*)(ws+o);    o+=(size_t)36864*2;
  float* out=(float*)d_out;

  hipLaunchKernelGGL(prep_k, dim3(1296),dim3(256),0,stream, counts,wk,wb);
  hipLaunchKernelGGL(hist_k, dim3(E_IN_N/256),dim3(256),0,stream, seg,succ,counts,cellrank);
  hipLaunchKernelGGL(blocksum_k, dim3(NB_SCAN),dim3(256),0,stream, counts,bsum);
  hipLaunchKernelGGL(offsets_k, dim3(NB_SCAN),dim3(256),0,stream, counts,bsum,offsets);
  hipLaunchKernelGGL(scatter_k, dim3(E_IN_N/256),dim3(256),0,stream, cellrank,dtv,offsets,sorted2);
  hipLaunchKernelGGL(compute_k, dim3(E_OUT_N/TILE_E),dim3(512),0,stream,
                     features,decay,bias,offsets,sorted2,wb,out);
}

// Round 15
// 178.477 us; speedup vs baseline: 1.6232x; 1.0335x over previous
//
#include <hip/hip_runtime.h>
#include <hip/hip_bf16.h>
#include <stdint.h>

#define E_IN_N   1048576
#define E_OUT_N  131072
#define KTAPS    9
#define CIN      64
#define COUT     64
#define NCELL    (E_OUT_N*KTAPS)   /* 1179648 */
#define NB_SCAN  1152              /* NCELL/1024 */
#define TILE_E   32
#define NKSTEP   18                /* 576/32 */
#define CHUNK    24

typedef __attribute__((ext_vector_type(8))) short bf16x8;
typedef __attribute__((ext_vector_type(4))) float f32x4;

__device__ __forceinline__ ushort f32_bf16(float x){
  union{float f; uint32_t u;} v; v.f=x;
  uint32_t r = v.u + 0x7FFFu + ((v.u>>16)&1u);
  return (ushort)(r>>16);
}

// fused: zero counts (blocks 0..1151) + W pre-permute (1152..1295)
__global__ void prep_k(int* __restrict__ counts, const float* __restrict__ wk,
                       ushort* __restrict__ wb){
  int b=blockIdx.x, t=threadIdx.x;
  if(b<1152){
    ((int4*)counts)[b*256+t]=int4{0,0,0,0};
  }else{
    int slot=(b-1152)*256+t;                 // 36864 total
    int j=slot&7; int t2=slot>>3; int lane=t2&63; int t3=t2>>6;
    int ks=t3%NKSTEP; int nt=t3/NKSTEP;
    int r=ks*32+((lane>>4)*8)+j; int col=nt*16+(lane&15);
    wb[slot]=f32_bf16(wk[r*COUT+col]);
  }
}

// histogram + per-event rank; cellrank = cell<<11 | rank  (cell<2^21, rank<2048)
__global__ void hist_k(const int* __restrict__ seg, const int* __restrict__ succ,
                       int* __restrict__ counts, uint32_t* __restrict__ cellrank){
  int i = blockIdx.x*256 + threadIdx.x;
  uint32_t cell = (uint32_t)(seg[i]*KTAPS + succ[i]);
  uint32_t rank = (uint32_t)atomicAdd(&counts[cell],1);
  cellrank[i] = (cell<<11) | rank;
}

__global__ void blocksum_k(const int* __restrict__ counts, int* __restrict__ bsum){
  __shared__ int sm[256];
  int b=blockIdx.x, t=threadIdx.x;
  const int4 c4 = *(const int4*)(counts + b*1024 + t*4);
  int s=c4.x+c4.y+c4.z+c4.w;
  sm[t]=s; __syncthreads();
  for(int d=128; d>0; d>>=1){ if(t<d) sm[t]+=sm[t+d]; __syncthreads(); }
  if(t==0) bsum[b]=sm[0];
}

// fused: block prefix over bsum + intra-block scan of counts -> offsets
__global__ void offsets_k(const int* __restrict__ counts, const int* __restrict__ bsum,
                          int* __restrict__ offsets){
  __shared__ int sm[256];
  int b=blockIdx.x, t=threadIdx.x;
  int s=0;
  for(int j=t; j<NB_SCAN; j+=256) if(j<b) s+=bsum[j];
  sm[t]=s; __syncthreads();
  for(int d=128; d>0; d>>=1){ if(t<d) sm[t]+=sm[t+d]; __syncthreads(); }
  int base0=sm[0]; __syncthreads();
  int base=b*1024+t*4;
  const int4 c4=*(const int4*)(counts+base);
  int s2=c4.x+c4.y+c4.z+c4.w;
  sm[t]=s2; __syncthreads();
  for(int d=1; d<256; d<<=1){ int x=(t>=d)?sm[t-d]:0; __syncthreads(); sm[t]+=x; __syncthreads(); }
  int e0v=base0 + ((t==0)?0:sm[t-1]);
  int4 o; o.x=e0v; o.y=e0v+c4.x; o.z=o.y+c4.y; o.w=o.z+c4.z;
  *(int4*)(offsets+base)=o;
  if(b==NB_SCAN-1 && t==255) offsets[NCELL]=o.w+c4.w;
}

// place events: pos = offsets[cell] + rank (no atomics); payload = idx|(cell%288)<<20, dt
__global__ void scatter_k(const uint32_t* __restrict__ cellrank, const float* __restrict__ dtv,
                          const int* __restrict__ offsets, int2* __restrict__ sorted2){
  int i=blockIdx.x*256+threadIdx.x;
  uint32_t cr=cellrank[i];
  uint32_t cell=cr>>11, rank=cr&2047u;
  int base=offsets[cell];
  float d=dtv[i];
  uint32_t x=cell>>5;
  uint32_t q=__umulhi(x,477218592u);          // /9  (exact for x<2^27)
  uint32_t rel=cell - q*288u;                 // cell % 288 (block-local)
  sorted2[base+(int)rank]=int2{(int)((uint32_t)i | (rel<<20)), __float_as_int(d)};
}

__global__ __launch_bounds__(512,4) void compute_k(
    const float* __restrict__ features, const float* __restrict__ decay,
    const float* __restrict__ bias, const int* __restrict__ offsets,
    const int2* __restrict__ sorted2, const ushort* __restrict__ wb,
    float* __restrict__ out)
{
  __shared__ ushort agg[TILE_E*584];   // 576 + 8 pad per row
  const int tid=threadIdx.x, wv=tid>>6, lane=tid&63;
  const int e0=blockIdx.x*TILE_E;
  const int cb0=e0*KTAPS;

  for(int i=tid;i<TILE_E*584/2;i+=512) ((uint32_t*)agg)[i]=0u;
  float x=decay[lane];
  float rate=fmaxf(x,0.f)+log1pf(__expf(-fabsf(x)));   // softplus
  __syncthreads();

  // ---- aggregation: wave owns 36 contiguous cells (rel in [wv*36, wv*36+36)) ----
  // Depth-1 branchless chunks of 24 (R7 structure, wider); scalar payload,
  // SGPR-based gather addresses, last-write-wins per-cell merge.
  {
    const int c0=cb0+wv*36;
    int jv=0; if(lane<2) jv=offsets[c0+lane*36];
    int cb = __builtin_amdgcn_readfirstlane(__shfl(jv,0));
    const int jE = __builtin_amdgcn_readfirstlane(__shfl(jv,1));

    int prevRel=-1;
    float num=0.f, den=1.f;

    while(cb<jE){
      int qx[CHUNK]; float qd[CHUNK];
      #pragma unroll
      for(int e=0;e<CHUNK;e++){            // uniform base -> scalar loads
        int2 t=sorted2[cb+e];
        qx[e]=t.x; qd[e]=__int_as_float(t.y);
      }
      float fl[CHUNK];
      #pragma unroll
      for(int e=0;e<CHUNK;e++){            // 24 gathers in flight; SGPR base + lane*4
        int iu = __builtin_amdgcn_readfirstlane(qx[e]) & 0xFFFFF;  // idx < 2^20 == E_IN
        fl[e] = features[((size_t)iu<<6) + lane];
      }
      #pragma unroll
      for(int e=0;e<CHUNK;e++){
        const int ok = (cb+e) < jE;        // scalar
        int rel = (int)(((uint32_t)qx[e])>>20);
        rel = ok ? rel : prevRel;          // pad: repeat last cell (harmless rewrite)
        float w = __expf(-qd[e]*rate);
        w = ok ? w : 0.f;                  // select AFTER exp: kills inf/NaN from pad garbage
        const float same = (rel==prevRel) ? 1.f : 0.f;
        num = num*same + w*fl[e];
        den = den*same + w;
        const int le=(rel*7282)>>16, kk=rel-le*9;
        agg[le*584 + kk*64 + lane] = f32_bf16(num*__builtin_amdgcn_rcpf(den));
        prevRel = rel;
      }
      cb += CHUNK;
    }
  }
  __syncthreads();

  // ---- GEMM: wave tile = 16 rows (mt) x 16 cols (nt), K=576 ----
  const int mt=wv>>2, nt=wv&3;
  const int arow=mt*16+(lane&15);
  const int koff=(lane>>4)*8;
  const ushort* wbp = wb + ((size_t)(nt*NKSTEP)*64 + (size_t)lane)*8;
  f32x4 acc={0.f,0.f,0.f,0.f};
  #pragma unroll
  for(int ks=0;ks<NKSTEP;ks++){
    bf16x8 a=*(const bf16x8*)&agg[arow*584+ks*32+koff];
    bf16x8 bfr=*(const bf16x8*)(wbp + (size_t)ks*512);
    acc=__builtin_amdgcn_mfma_f32_16x16x32_bf16(a,bfr,acc,0,0,0);
  }
  const int orow=e0+mt*16+((lane>>4)*4);
  const int ocol=nt*16+(lane&15);
  const float bv=bias[ocol];
  #pragma unroll
  for(int r=0;r<4;r++) out[(size_t)(orow+r)*COUT+ocol]=acc[r]+bv;
}

extern "C" void kernel_launch(void* const* d_in, const int* in_sizes, int n_in,
                              void* d_out, int out_size, void* d_ws, size_t ws_size,
                              hipStream_t stream){
  const float* features=(const float*)d_in[0];
  const float* dtv=(const float*)d_in[1];
  const float* decay=(const float*)d_in[3];
  const float* wk=(const float*)d_in[4];
  const float* bias=(const float*)d_in[5];
  const int* succ=(const int*)d_in[6];
  const int* seg=(const int*)d_in[7];

  char* ws=(char*)d_ws;
  size_t o=0;
  int* counts=(int*)(ws+o);      o+=(size_t)NCELL*4;
  int* offsets=(int*)(ws+o);     o+=(size_t)(NCELL+4)*4;
  int* bsum=(int*)(ws+o);        o+=(size_t)NB_SCAN*4;
  uint32_t* cellrank=(uint32_t*)(ws+o); o+=(size_t)E_IN_N*4;
  int2* sorted2=(int2*)(ws+o);   o+=(size_t)(E_IN_N+64)*8;   // slack for padded chunk reads
  ushort* wb=(ushort*)(ws+o);    o+=(size_t)36864*2;
  float* out=(float*)d_out;

  hipLaunchKernelGGL(prep_k, dim3(1296),dim3(256),0,stream, counts,wk,wb);
  hipLaunchKernelGGL(hist_k, dim3(E_IN_N/256),dim3(256),0,stream, seg,succ,counts,cellrank);
  hipLaunchKernelGGL(blocksum_k, dim3(NB_SCAN),dim3(256),0,stream, counts,bsum);
  hipLaunchKernelGGL(offsets_k, dim3(NB_SCAN),dim3(256),0,stream, counts,bsum,offsets);
  hipLaunchKernelGGL(scatter_k, dim3(E_IN_N/256),dim3(256),0,stream, cellrank,dtv,offsets,sorted2);
  hipLaunchKernelGGL(compute_k, dim3(E_OUT_N/TILE_E),dim3(512),0,stream,
                     features,decay,bias,offsets,sorted2,wb,out);
}